// Round 2
// baseline (551.798 us; speedup 1.0000x reference)
//
#include <hip/hip_runtime.h>

#define BB 16
#define LL 2048
#define HH 1024
#define ZZ 512
#define NEGV -1e9f

// k[b,h'] = sum_h efhs[b,h] * Wk[h,h']   (grid 64 x 256; coalesced over h')
__global__ void k_proj_k(const float* __restrict__ efhs,
                         const float* __restrict__ Wk,
                         float* __restrict__ kout) {
    int idx = blockIdx.x * 256 + threadIdx.x;   // b*H + h'
    int b = idx >> 10, hp = idx & 1023;
    const float* e = efhs + b * HH;
    float acc = 0.f;
    for (int h = 0; h < HH; ++h)
        acc += e[h] * Wk[h * HH + hp];
    kout[idx] = acc;
}

// kq[b,h] = sum_h' Wq[h,h'] * k[b,h']    (wave per row, float4)
__global__ void k_proj_kq(const float* __restrict__ Wq,
                          const float* __restrict__ kin,
                          float* __restrict__ kq) {
    int row = blockIdx.x * 4 + (threadIdx.x >> 6);  // b*H + h
    int lane = threadIdx.x & 63;
    int b = row >> 10, h = row & 1023;
    const float4* wrow = (const float4*)(Wq + (size_t)h * HH);
    const float4* kb = (const float4*)(kin + b * HH);
    float acc = 0.f;
#pragma unroll
    for (int u = 0; u < 4; ++u) {
        float4 wv = wrow[u * 64 + lane];
        float4 kv = kb[u * 64 + lane];
        acc += wv.x * kv.x + wv.y * kv.y + wv.z * kv.z + wv.w * kv.w;
    }
    for (int off = 32; off > 0; off >>= 1) acc += __shfl_down(acc, off);
    if (lane == 0) kq[row] = acc;
}

// zsum[b,z0] += sum over 64-row j-chunk of z[b,j,z0]  (grid B*32 x 512)
__global__ void k_zsum(const float* __restrict__ zseq,
                       float* __restrict__ zsum) {
    int b = blockIdx.x >> 5;
    int jc = blockIdx.x & 31;
    int z0 = threadIdx.x;  // 512 threads
    const float* p = zseq + ((size_t)(b * LL + jc * 64)) * ZZ + z0;
    float acc = 0.f;
    for (int j = 0; j < 64; ++j) acc += p[(size_t)j * ZZ];
    atomicAdd(&zsum[b * ZZ + z0], acc);
}

// Vs[b,z] = sum_z0 zsum[b,z0] * Wv[z0,z]   (grid 32 x 256; coalesced over z)
__global__ void k_vsum(const float* __restrict__ zsum,
                       const float* __restrict__ Wv,
                       float* __restrict__ Vs) {
    int idx = blockIdx.x * 256 + threadIdx.x;   // b*Z + z
    int b = idx >> 9, z = idx & 511;
    const float* zs = zsum + b * ZZ;
    float acc = 0.f;
    for (int z0 = 0; z0 < ZZ; ++z0) acc += zs[z0] * Wv[z0 * ZZ + z];
    Vs[idx] = acc;
}

// s[b,i] = (erhs[b,i] . kq[b]) / 32, masked  (wave per row, float4)
__global__ void k_scores(const float* __restrict__ erhs,
                         const float* __restrict__ kq,
                         const int* __restrict__ mask,
                         float* __restrict__ s) {
    int row = blockIdx.x * 4 + (threadIdx.x >> 6);  // b*L + i
    int lane = threadIdx.x & 63;
    int b = row >> 11;
    const float4* e = (const float4*)(erhs + (size_t)row * HH);
    const float4* kb = (const float4*)(kq + b * HH);
    float acc = 0.f;
#pragma unroll
    for (int u = 0; u < 4; ++u) {
        float4 ev = e[u * 64 + lane];
        float4 kv = kb[u * 64 + lane];
        acc += ev.x * kv.x + ev.y * kv.y + ev.z * kv.z + ev.w * kv.w;
    }
    for (int off = 32; off > 0; off >>= 1) acc += __shfl_down(acc, off);
    if (lane == 0) {
        float v = acc * (1.0f / 32.0f);
        if (mask[row] == 0) v = NEGV;
        s[row] = v;
    }
}

// w[b,:] = softmax over i of s[b,:]   (one block of 256 per b)
__global__ void k_softmax(const float* __restrict__ s, float* __restrict__ w) {
    __shared__ float es[LL];
    __shared__ float red[16];
    int b = blockIdx.x, tid = threadIdx.x;
    int wave = tid >> 6, lane = tid & 63;
    const float* sb = s + b * LL;
    float m = -3.4e38f;
    for (int i = tid; i < LL; i += 256) m = fmaxf(m, sb[i]);
    for (int off = 32; off > 0; off >>= 1) m = fmaxf(m, __shfl_down(m, off));
    if (lane == 0) red[wave] = m;
    __syncthreads();
    if (tid == 0) {
        float mm = red[0];
        for (int i = 1; i < 4; ++i) mm = fmaxf(mm, red[i]);
        red[0] = mm;
    }
    __syncthreads();
    m = red[0];
    float ssum = 0.f;
    for (int i = tid; i < LL; i += 256) {
        float e = __expf(sb[i] - m);
        es[i] = e;
        ssum += e;
    }
    for (int off = 32; off > 0; off >>= 1) ssum += __shfl_down(ssum, off);
    if (lane == 0) red[8 + wave] = ssum;
    __syncthreads();
    if (tid == 0) {
        float t = 0.f;
        for (int i = 0; i < 4; ++i) t += red[8 + i];
        red[8] = t;
    }
    __syncthreads();
    float inv = 1.0f / red[8];
    for (int i = tid; i < LL; i += 256) w[b * LL + i] = es[i] * inv;
}

// output[b,i,z] = w[b,i] * Vs[b,z]   (float4 stores; grid 16384 x 256)
__global__ void k_out(const float* __restrict__ w, const float* __restrict__ Vs,
                      float* __restrict__ out) {
    int idx = blockIdx.x * 256 + threadIdx.x;   // B*L*Z/4 float4s
    int b = idx >> 18;                          // L*Z/4 = 262144 per b
    int rem = idx & 262143;
    int i = rem >> 7, zv = rem & 127;           // Z/4 = 128 float4 per row
    float wv = w[b * LL + i];
    float4 v = ((const float4*)(Vs + b * ZZ))[zv];
    ((float4*)out)[idx] = make_float4(wv * v.x, wv * v.y, wv * v.z, wv * v.w);
}

// attn[b,i,j] = w[b,i]   (one block per row; 2 x float4 per thread)
__global__ void k_attn(const float* __restrict__ w, float* __restrict__ attn) {
    int row = blockIdx.x;        // b*L + i
    float v = w[row];
    float4 pk = make_float4(v, v, v, v);
    float4* p = (float4*)attn + (size_t)row * 512;   // L/4 = 512 float4 per row
    p[threadIdx.x] = pk;
    p[threadIdx.x + 256] = pk;
}

extern "C" void kernel_launch(void* const* d_in, const int* in_sizes, int n_in,
                              void* d_out, int out_size, void* d_ws, size_t ws_size,
                              hipStream_t stream) {
    const float* erhs = (const float*)d_in[0];  // [B,L,H]
    const float* efhs = (const float*)d_in[1];  // [B,H]
    const float* zseq = (const float*)d_in[2];  // [B,L,Z]
    const int*   mask = (const int*)d_in[3];    // [B,L]
    const float* Wq   = (const float*)d_in[4];  // [H,H]
    const float* Wk   = (const float*)d_in[5];  // [H,H]
    const float* Wv   = (const float*)d_in[6];  // [Z,Z]
    float* out = (float*)d_out;

    float* ws   = (float*)d_ws;
    float* zsum = ws;            // 8192 floats
    float* kbuf = ws + 8192;     // 16384
    float* kq   = ws + 24576;    // 16384
    float* Vs   = ws + 40960;    // 8192
    float* sbuf = ws + 49152;    // 32768
    float* wbuf = ws + 81920;    // 32768

    hipMemsetAsync(zsum, 0, 8192 * sizeof(float), stream);
    k_proj_k <<<   64, 256, 0, stream>>>(efhs, Wk, kbuf);
    k_proj_kq<<< 4096, 256, 0, stream>>>(Wq, kbuf, kq);
    k_zsum   <<<  512, 512, 0, stream>>>(zseq, zsum);
    k_vsum   <<<   32, 256, 0, stream>>>(zsum, Wv, Vs);
    k_scores <<< 8192, 256, 0, stream>>>(erhs, kq, mask, sbuf);
    k_softmax<<<   16, 256, 0, stream>>>(sbuf, wbuf);
    k_out    <<<16384, 256, 0, stream>>>(wbuf, Vs, out);
    k_attn   <<<32768, 256, 0, stream>>>(wbuf, out + (size_t)BB * LL * ZZ);
}

// Round 3
// 503.399 us; speedup vs baseline: 1.0961x; 1.0961x over previous
//
#include <hip/hip_runtime.h>

#define BB 16
#define LL 2048
#define HH 1024
#define ZZ 512
#define NEGV -1e9f

// Stage A: kbuf[b,hp] = sum_h efhs[b,h]*Wk[h,hp]  (split reduction, atomic combine)
// grid 512 = b(16) x hp-chunk(4 x 256) x h-chunk(8 x 128)
__global__ __launch_bounds__(256) void k_proj_k(const float* __restrict__ efhs,
                                                const float* __restrict__ Wk,
                                                float* __restrict__ kbuf) {
    int blk = blockIdx.x;
    int b   = blk >> 5;
    int hpc = (blk >> 3) & 3;
    int hc  = blk & 7;
    int hp  = hpc * 256 + threadIdx.x;
    const float* e  = efhs + b * HH + hc * 128;
    const float* wk = Wk + (size_t)(hc * 128) * HH + hp;
    float acc = 0.f;
#pragma unroll 4
    for (int h = 0; h < 128; ++h)
        acc += e[h] * wk[(size_t)h * HH];
    atomicAdd(&kbuf[b * HH + hp], acc);
}

// Stage B: kq[b,h] = Wq[h,:] . kbuf[b,:]
// grid 4096 = h(1024) x bgroup(4); the block's 4 waves share the same Wq row (L1 reuse)
__global__ __launch_bounds__(256) void k_proj_kq(const float* __restrict__ Wq,
                                                 const float* __restrict__ kbuf,
                                                 float* __restrict__ kq) {
    int h = blockIdx.x >> 2;
    int b = ((blockIdx.x & 3) << 2) + (threadIdx.x >> 6);
    int lane = threadIdx.x & 63;
    const float4* wrow = (const float4*)(Wq + (size_t)h * HH);
    const float4* kb   = (const float4*)(kbuf + b * HH);
    float acc = 0.f;
#pragma unroll
    for (int u = 0; u < 4; ++u) {
        float4 wv = wrow[u * 64 + lane];
        float4 kv = kb[u * 64 + lane];
        acc += wv.x * kv.x + wv.y * kv.y + wv.z * kv.z + wv.w * kv.w;
    }
    for (int off = 32; off > 0; off >>= 1) acc += __shfl_down(acc, off);
    if (lane == 0) kq[b * HH + h] = acc;
}

// Stage C (fused): blocks [0,8192): s[b,i] = (erhs[b,i].kq[b])/32, masked
//                  blocks [8192,8704): zsum[b,z0] += 64-row chunk of zseq
__global__ __launch_bounds__(256) void k_scores_zsum(const float* __restrict__ erhs,
                                                     const float* __restrict__ kq,
                                                     const int* __restrict__ mask,
                                                     const float* __restrict__ zseq,
                                                     float* __restrict__ sbuf,
                                                     float* __restrict__ zsum) {
    if (blockIdx.x < 8192) {
        int row = blockIdx.x * 4 + (threadIdx.x >> 6);  // b*L + i
        int lane = threadIdx.x & 63;
        int b = row >> 11;
        const float4* e  = (const float4*)(erhs + (size_t)row * HH);
        const float4* kb = (const float4*)(kq + b * HH);
        float acc = 0.f;
#pragma unroll
        for (int u = 0; u < 4; ++u) {
            float4 ev = e[u * 64 + lane];
            float4 kv = kb[u * 64 + lane];
            acc += ev.x * kv.x + ev.y * kv.y + ev.z * kv.z + ev.w * kv.w;
        }
        for (int off = 32; off > 0; off >>= 1) acc += __shfl_down(acc, off);
        if (lane == 0) {
            float v = acc * (1.0f / 32.0f);
            if (mask[row] == 0) v = NEGV;
            sbuf[row] = v;
        }
    } else {
        int blk = blockIdx.x - 8192;   // [0,512): b(16) x j-chunk(32 x 64)
        int b = blk >> 5, jc = blk & 31;
        int t = threadIdx.x;
        const float* p = zseq + ((size_t)(b * LL + jc * 64)) * ZZ;
        float a0 = 0.f, a1 = 0.f;
        for (int j = 0; j < 64; ++j) {
            const float* pj = p + (size_t)j * ZZ;
            a0 += pj[t];
            a1 += pj[t + 256];
        }
        atomicAdd(&zsum[b * ZZ + t], a0);
        atomicAdd(&zsum[b * ZZ + t + 256], a1);
    }
}

// Stage D (fused): blocks [0,16): w[b,:] = softmax_i(s[b,:])
//                  blocks [16,144): Vs[b,z] += (z0-chunk) zsum[b,z0]*Wv[z0,z]
__global__ __launch_bounds__(256) void k_softmax_vsum(const float* __restrict__ sbuf,
                                                      const float* __restrict__ zsum,
                                                      const float* __restrict__ Wv,
                                                      float* __restrict__ wbuf,
                                                      float* __restrict__ Vs) {
    __shared__ float es[LL];
    __shared__ float red[16];
    if (blockIdx.x < 16) {
        int b = blockIdx.x, tid = threadIdx.x;
        int wave = tid >> 6, lane = tid & 63;
        const float* sb = sbuf + b * LL;
        float m = -3.4e38f;
        for (int i = tid; i < LL; i += 256) m = fmaxf(m, sb[i]);
        for (int off = 32; off > 0; off >>= 1) m = fmaxf(m, __shfl_down(m, off));
        if (lane == 0) red[wave] = m;
        __syncthreads();
        if (tid == 0) {
            float mm = red[0];
            for (int i = 1; i < 4; ++i) mm = fmaxf(mm, red[i]);
            red[0] = mm;
        }
        __syncthreads();
        m = red[0];
        float ssum = 0.f;
        for (int i = tid; i < LL; i += 256) {
            float e = __expf(sb[i] - m);
            es[i] = e;
            ssum += e;
        }
        for (int off = 32; off > 0; off >>= 1) ssum += __shfl_down(ssum, off);
        if (lane == 0) red[8 + wave] = ssum;
        __syncthreads();
        if (tid == 0) {
            float tt = 0.f;
            for (int i = 0; i < 4; ++i) tt += red[8 + i];
            red[8] = tt;
        }
        __syncthreads();
        float inv = 1.0f / red[8];
        for (int i = tid; i < LL; i += 256) wbuf[b * LL + i] = es[i] * inv;
    } else {
        int blk = blockIdx.x - 16;     // [0,128): b(16) x z0-chunk(8 x 64)
        int b = blk >> 3, z0c = blk & 7;
        int t = threadIdx.x;
        const float* zs = zsum + b * ZZ + z0c * 64;
        const float* wv = Wv + (size_t)(z0c * 64) * ZZ;
        float a0 = 0.f, a1 = 0.f;
        for (int z0 = 0; z0 < 64; ++z0) {
            float zv = zs[z0];
            const float* wr = wv + (size_t)z0 * ZZ;
            a0 += zv * wr[t];
            a1 += zv * wr[t + 256];
        }
        atomicAdd(&Vs[b * ZZ + t], a0);
        atomicAdd(&Vs[b * ZZ + t + 256], a1);
    }
}

// Stage E (fused epilogue): one block per (b,i) row.
//   out[b,i,:]  = w[b,i] * Vs[b,:]      (128 float4)
//   attn[b,i,:] = w[b,i] broadcast      (512 float4)
__global__ __launch_bounds__(256) void k_outattn(const float* __restrict__ wbuf,
                                                 const float* __restrict__ Vs,
                                                 float* __restrict__ out,
                                                 float* __restrict__ attn) {
    int row = blockIdx.x;          // b*L + i
    int b = row >> 11;
    int t = threadIdx.x;
    float wv = wbuf[row];
    if (t < 128) {
        float4 v = ((const float4*)(Vs + b * ZZ))[t];
        ((float4*)(out + (size_t)row * ZZ))[t] =
            make_float4(wv * v.x, wv * v.y, wv * v.z, wv * v.w);
    }
    float4 pk = make_float4(wv, wv, wv, wv);
    float4* p = (float4*)attn + (size_t)row * 512;
    p[t]       = pk;
    p[t + 256] = pk;
}

extern "C" void kernel_launch(void* const* d_in, const int* in_sizes, int n_in,
                              void* d_out, int out_size, void* d_ws, size_t ws_size,
                              hipStream_t stream) {
    const float* erhs = (const float*)d_in[0];  // [B,L,H]
    const float* efhs = (const float*)d_in[1];  // [B,H]
    const float* zseq = (const float*)d_in[2];  // [B,L,Z]
    const int*   mask = (const int*)d_in[3];    // [B,L]
    const float* Wq   = (const float*)d_in[4];  // [H,H]
    const float* Wk   = (const float*)d_in[5];  // [H,H]
    const float* Wv   = (const float*)d_in[6];  // [Z,Z]
    float* out = (float*)d_out;

    float* ws   = (float*)d_ws;
    float* zsum = ws;             //  8192 floats  (zeroed)
    float* kbuf = ws + 8192;      // 16384 floats  (zeroed)
    float* Vs   = ws + 24576;     //  8192 floats  (zeroed)
    float* sbuf = ws + 32768;     // 32768 floats
    float* wbuf = ws + 65536;     // 32768 floats
    float* kq   = ws + 98304;     // 16384 floats

    hipMemsetAsync(ws, 0, 32768 * sizeof(float), stream);  // zsum+kbuf+Vs
    k_proj_k      <<<  512, 256, 0, stream>>>(efhs, Wk, kbuf);
    k_proj_kq     <<< 4096, 256, 0, stream>>>(Wq, kbuf, kq);
    k_scores_zsum <<< 8704, 256, 0, stream>>>(erhs, kq, mask, zseq, sbuf, zsum);
    k_softmax_vsum<<<  144, 256, 0, stream>>>(sbuf, zsum, Wv, wbuf, Vs);
    k_outattn     <<<32768, 256, 0, stream>>>(wbuf, Vs, out,
                                              out + (size_t)BB * LL * ZZ);
}